// Round 6
// baseline (479.820 us; speedup 1.0000x reference)
//
#include <hip/hip_runtime.h>
#include <hip/hip_cooperative_groups.h>
#include <cmath>

namespace cg = cooperative_groups;

#define TAPE_SZ 100000
#define N_SZ    50000
#define F_SZ    32
#define B_SZ    128
#define RANGE   25000      // tape rows per phase; slice/XCD = 25000*64b*2B = 3.2 MB (L2-fit)
#define NBV     128        // n's per block
#define NCHUNK  391        // ceil(50000/128)
#define GRID_G  (NCHUNK*2) // x2 b-halves = 782 blocks (<= 4/CU x 256 CU cooperative capacity)
#define NTAIL   512
#define TAIL_F4 1600000    // 128 b * 12500 float4 tail elements

// Manual round-to-nearest-even f32 -> bf16 bits.
static __device__ __forceinline__ unsigned short f32_to_bf16(float f) {
    unsigned int u = __float_as_uint(f);
    u = (u + 0x7fffu + ((u >> 16) & 1u)) >> 16;
    return (unsigned short)u;
}

// ---------------------------------------------------------------------------
// Transpose tape (B x TAPE fp32) -> tapeF[row][b] bf16 (full 256-B rows).
// ---------------------------------------------------------------------------
__global__ __launch_bounds__(256) void transpose_full(const float* __restrict__ in,
                                                      unsigned short* __restrict__ outF) {
    __shared__ float tile[32][129];
    const int x0 = blockIdx.x * 32;
    const int tx = threadIdx.x;       // tape-col 0..31
    const int ty = threadIdx.y;       // 0..7

    #pragma unroll
    for (int yy = ty; yy < B_SZ; yy += 8)
        tile[tx][yy] = in[(size_t)yy * TAPE_SZ + x0 + tx];
    __syncthreads();

    const int tid = ty * 32 + tx;
    const int l = tid >> 3, o = tid & 7;
    unsigned short* dst = outF + (size_t)(x0 + l) * B_SZ + o * 8;
    union { unsigned short u[8]; uint4 q; } p0, p1;
    #pragma unroll
    for (int k = 0; k < 8; ++k) {
        p0.u[k] = f32_to_bf16(tile[l][o * 8 + k]);
        p1.u[k] = f32_to_bf16(tile[l][64 + o * 8 + k]);
    }
    *(uint4*)dst        = p0.q;
    *(uint4*)(dst + 64) = p1.q;
}

// ---------------------------------------------------------------------------
// Cooperative phased gather. Block = (chunk of 128 n, b-half h). Thread =
// (n_local, b-quarter-of-half): 32 f32 accumulators, 64 B (4x dwordx4) per
// entry; 2 lanes/n consume one full 128-B line. Entries counting-sorted by
// tape range (4 buckets) in LDS; phase r processes only range-r entries, so
// each XCD's live tape slice is 3.2 MB -> L2-resident. grid.sync() between
// phases keeps all blocks in the same range. Line-misses: 3.2M vs 12.8M.
// ---------------------------------------------------------------------------
__global__ __launch_bounds__(256, 4) void gather_phased(
    const unsigned short* __restrict__ tapeF,
    const float* __restrict__ weights,
    const float* __restrict__ bias,
    const int*   __restrict__ in_idx,
    const int*   __restrict__ out_idx,
    const int*   __restrict__ act_type,
    const float* __restrict__ tape,
    float* __restrict__ out) {
    __shared__ union {
        struct {
            uint2 ent[NBV][33];    // sorted (.x = tape idx, .y = weight bits); pitch 33
            int   start[NBV][5];   // bucket boundaries per n (start[.][4] = total)
        } s;                       // 36352 B
        float x[64][132];          // epilogue stage [b_local][n], aliased (33792 B)
    } u;
    __shared__ int   s_oidx[NBV];
    __shared__ float s_bias[NBV];
    __shared__ int   s_act[NBV];

    const int tid   = threadIdx.x;
    const int h     = blockIdx.x & 1;     // b-half; == XCD parity (blockIdx%8 round-robin)
    const int chunk = blockIdx.x >> 1;
    const int n0    = chunk * NBV;
    const int nend  = min(NBV, N_SZ - n0);

    // ---- stage + counting-sort entries by range (one thread per n) ----
    if (tid < NBV) {
        if (tid < nend) {
            const int*   ip = in_idx  + (size_t)(n0 + tid) * 32;
            const float* wp = weights + (size_t)(n0 + tid) * 32;
            int ix[32];
            #pragma unroll
            for (int f = 0; f < 32; ++f) ix[f] = ip[f];
            int c0 = 0, c1 = 0, c2 = 0, c3 = 0;
            #pragma unroll
            for (int f = 0; f < 32; ++f) {
                const int r = ix[f] / RANGE;
                c0 += (r == 0); c1 += (r == 1); c2 += (r == 2); c3 += (r == 3);
            }
            int o0 = 0, o1 = c0, o2 = c0 + c1, o3 = c0 + c1 + c2;
            u.s.start[tid][0] = 0;  u.s.start[tid][1] = o1;
            u.s.start[tid][2] = o2; u.s.start[tid][3] = o3;
            u.s.start[tid][4] = 32;
            #pragma unroll
            for (int f = 0; f < 32; ++f) {
                const int r = ix[f] / RANGE;
                int pos;
                if      (r == 0) pos = o0++;
                else if (r == 1) pos = o1++;
                else if (r == 2) pos = o2++;
                else             pos = o3++;
                u.s.ent[tid][pos] = make_uint2((unsigned)ix[f], __float_as_uint(wp[f]));
            }
            s_oidx[tid] = out_idx[n0 + tid];
            s_bias[tid] = bias[n0 + tid];
            s_act[tid]  = act_type[n0 + tid];
        } else {
            #pragma unroll
            for (int r = 0; r < 5; ++r) u.s.start[tid][r] = 0;
        }
    }
    __syncthreads();

    const int nl = tid >> 1;              // n_local 0..127
    const int bq = tid & 1;               // b-quarter within half: 32 b's
    const unsigned short* tg = tapeF + h * 64 + bq * 32;

    float a[32];
    #pragma unroll
    for (int j = 0; j < 32; ++j) a[j] = 0.f;

    cg::grid_group grid = cg::this_grid();

    #pragma unroll 1
    for (int r = 0; r < 4; ++r) {
        const int e0 = u.s.start[nl][r];
        const int e1 = u.s.start[nl][r + 1];
        for (int e = e0; e < e1; ++e) {
            const uint2 iw = u.s.ent[nl][e];
            const unsigned short* p = tg + (size_t)iw.x * B_SZ;
            const uint4 q0 = *(const uint4*)(p +  0);
            const uint4 q1 = *(const uint4*)(p +  8);
            const uint4 q2 = *(const uint4*)(p + 16);
            const uint4 q3 = *(const uint4*)(p + 24);
            const float wv = __uint_as_float(iw.y);
#define ACC8(Q, B0) \
            a[B0+0] = fmaf(__uint_as_float((Q).x << 16),          wv, a[B0+0]); \
            a[B0+1] = fmaf(__uint_as_float((Q).x & 0xffff0000u),  wv, a[B0+1]); \
            a[B0+2] = fmaf(__uint_as_float((Q).y << 16),          wv, a[B0+2]); \
            a[B0+3] = fmaf(__uint_as_float((Q).y & 0xffff0000u),  wv, a[B0+3]); \
            a[B0+4] = fmaf(__uint_as_float((Q).z << 16),          wv, a[B0+4]); \
            a[B0+5] = fmaf(__uint_as_float((Q).z & 0xffff0000u),  wv, a[B0+5]); \
            a[B0+6] = fmaf(__uint_as_float((Q).w << 16),          wv, a[B0+6]); \
            a[B0+7] = fmaf(__uint_as_float((Q).w & 0xffff0000u),  wv, a[B0+7]);
            ACC8(q0, 0) ACC8(q1, 8) ACC8(q2, 16) ACC8(q3, 24)
#undef ACC8
        }
        if (r < 3) grid.sync();           // uniform: every block reaches this
    }

    // ---- bias + activation ----
    {
        const float bz = (nl < nend) ? s_bias[nl] : 0.f;
        const int   at = (nl < nend) ? s_act[nl]  : 0;
        #pragma unroll
        for (int j = 0; j < 32; ++j) {
            const float v = a[j] + bz;
            a[j] = (at == 0) ? fmaxf(v, 0.f) : tanhf(v);
        }
    }
    __syncthreads();   // all ent/start reads done before aliased x writes
    if (nl < nend) {
        #pragma unroll
        for (int j = 0; j < 32; ++j)
            u.x[bq * 32 + j][nl] = a[j];
    }
    __syncthreads();

    // ---- epilogue: coalesced float4 row stores (consec out_idx fast path) ----
    const int quads = (nend + 3) >> 2;
    for (int it = tid; it < 64 * quads; it += 256) {
        int bsub, j4;
        if (nend == NBV) { bsub = it >> 5; j4 = it & 31; }
        else             { bsub = it / quads; j4 = it - bsub * quads; }
        const int nq  = j4 * 4;
        const int oc0 = s_oidx[nq];
        float* orow = out + (size_t)(h * 64 + bsub) * TAPE_SZ;
        const bool consec = (nq + 3 < nend) &&
                            (s_oidx[nq + 1] == oc0 + 1) &&
                            (s_oidx[nq + 2] == oc0 + 2) &&
                            (s_oidx[nq + 3] == oc0 + 3) && ((oc0 & 3) == 0);
        if (consec) {
            *(float4*)(orow + oc0) = *(const float4*)&u.x[bsub][nq];
        } else {
            #pragma unroll
            for (int c = 0; c < 4; ++c)
                if (nq + c < nend) orow[s_oidx[nq + c]] = u.x[bsub][nq + c];
        }
    }

    // ---- tail copy: columns [N_SZ, TAPE_SZ) survive into out ----
    {
        const int stride = GRID_G * 256;
        for (int i = blockIdx.x * 256 + tid; i < TAIL_F4; i += stride) {
            const int bb = i / 12500;
            const int j  = i - bb * 12500;
            const size_t off = (size_t)bb * (TAPE_SZ / 4) + (N_SZ / 4) + j;
            ((float4*)out)[off] = ((const float4*)tape)[off];
        }
    }
}

// ---------------------------------------------------------------------------
// Tier-2 fallback: R1's proven L2-partitioned path (85 us).
// ---------------------------------------------------------------------------
#define NGRP    8
#define GSUB    16
#define NBV2    64
#define NCHUNK2 ((N_SZ + NBV2 - 1) / NBV2)
#define NGATH2  (NCHUNK2 * NGRP)

__global__ __launch_bounds__(256) void transpose_part(const float* __restrict__ in,
                                                      unsigned short* __restrict__ outT) {
    __shared__ float tile[32][129];
    const int x0 = blockIdx.x * 32;
    const int tx = threadIdx.x, ty = threadIdx.y;
    #pragma unroll
    for (int yy = ty; yy < B_SZ; yy += 8)
        tile[tx][yy] = in[(size_t)yy * TAPE_SZ + x0 + tx];
    __syncthreads();
    const int tid = ty * 32 + tx;
    const int g = tid >> 5, l = tid & 31;
    unsigned short* dst = outT + ((size_t)g * TAPE_SZ + x0 + l) * GSUB;
    union { unsigned short u[8]; uint4 q; } p0, p1;
    #pragma unroll
    for (int k = 0; k < 8; ++k) {
        p0.u[k] = f32_to_bf16(tile[l][g * GSUB + k]);
        p1.u[k] = f32_to_bf16(tile[l][g * GSUB + 8 + k]);
    }
    *(uint4*)dst = p0.q; *(uint4*)(dst + 8) = p1.q;
}

__global__ __launch_bounds__(256, 8) void gather_mm_part(const unsigned short* __restrict__ tapeT,
                                                         const float* __restrict__ weights,
                                                         const float* __restrict__ bias,
                                                         const int*   __restrict__ in_idx,
                                                         const int*   __restrict__ out_idx,
                                                         const int*   __restrict__ act_type,
                                                         const float* __restrict__ tape,
                                                         float* __restrict__ out) {
    __shared__ int2  s_iw[NBV2][33];
    __shared__ float s_bias[NBV2];
    __shared__ int   s_act[NBV2];
    __shared__ int   s_oidx[NBV2];
    float (*s_x)[68] = (float (*)[68])&s_iw[0][0];
    const int tid = threadIdx.x;

    if (blockIdx.x >= NGATH2) {
        const float4* src = (const float4*)tape;
        float4*       dst = (float4*)out;
        const int stride = NTAIL * 256;
        for (int i = (blockIdx.x - NGATH2) * 256 + tid; i < TAIL_F4; i += stride) {
            const int b = i / 12500;
            const int j = i - b * 12500;
            const int off = b * (TAPE_SZ / 4) + (N_SZ / 4) + j;
            dst[off] = src[off];
        }
        return;
    }
    const int g = blockIdx.x & (NGRP - 1);
    const int chunk = blockIdx.x >> 3;
    const int n0 = chunk * NBV2;
    const int nend = min(NBV2, N_SZ - n0);

    for (int t = tid; t < nend * 32; t += 256) {
        const int n = t >> 5, f = t & 31;
        s_iw[n][f] = make_int2(in_idx[(size_t)n0 * 32 + t],
                               __float_as_int(weights[(size_t)n0 * 32 + t]));
    }
    if (tid < nend) {
        s_bias[tid] = bias[n0 + tid];
        s_act[tid]  = act_type[n0 + tid];
        s_oidx[tid] = out_idx[n0 + tid];
    }
    __syncthreads();

    const int nl = tid >> 2, q = tid & 3;
    const unsigned short* tg = tapeT + (size_t)g * TAPE_SZ * GSUB + q * 4;
    float a0 = 0.f, a1 = 0.f, a2 = 0.f, a3 = 0.f;
    if (nl < nend) {
        #pragma unroll
        for (int fo = 0; fo < 32; fo += 8) {
            int2 iw8[8];
            #pragma unroll
            for (int j = 0; j < 8; ++j) iw8[j] = s_iw[nl][fo + j];
            uint2 q8[8];
            #pragma unroll
            for (int j = 0; j < 8; ++j)
                q8[j] = *(const uint2*)(tg + (size_t)iw8[j].x * GSUB);
            #pragma unroll
            for (int j = 0; j < 8; ++j) {
                const float w = __int_as_float(iw8[j].y);
                a0 = fmaf(__uint_as_float(q8[j].x << 16),         w, a0);
                a1 = fmaf(__uint_as_float(q8[j].x & 0xffff0000u), w, a1);
                a2 = fmaf(__uint_as_float(q8[j].y << 16),         w, a2);
                a3 = fmaf(__uint_as_float(q8[j].y & 0xffff0000u), w, a3);
            }
        }
        const float bz = s_bias[nl];
        a0 += bz; a1 += bz; a2 += bz; a3 += bz;
        if (s_act[nl] == 0) {
            a0 = fmaxf(a0, 0.f); a1 = fmaxf(a1, 0.f);
            a2 = fmaxf(a2, 0.f); a3 = fmaxf(a3, 0.f);
        } else {
            a0 = tanhf(a0); a1 = tanhf(a1); a2 = tanhf(a2); a3 = tanhf(a3);
        }
    }
    __syncthreads();
    if (nl < nend) {
        const int bs = q * 4;
        s_x[bs + 0][nl] = a0; s_x[bs + 1][nl] = a1;
        s_x[bs + 2][nl] = a2; s_x[bs + 3][nl] = a3;
    }
    __syncthreads();
    const int quads = (nend + 3) >> 2;
    for (int idx = tid; idx < GSUB * quads; idx += 256) {
        int bsub, j4;
        if (nend == NBV2) { bsub = idx >> 4; j4 = idx & 15; }
        else              { bsub = idx / quads; j4 = idx - bsub * quads; }
        const int nq = j4 * 4;
        const int oc0 = s_oidx[nq];
        float* orow = out + (size_t)(g * GSUB + bsub) * TAPE_SZ;
        const bool consec = (nq + 3 < nend) &&
                            (s_oidx[nq + 1] == oc0 + 1) && (s_oidx[nq + 2] == oc0 + 2) &&
                            (s_oidx[nq + 3] == oc0 + 3) && ((oc0 & 3) == 0);
        if (consec) {
            *(float4*)(orow + oc0) = make_float4(s_x[bsub][nq + 0], s_x[bsub][nq + 1],
                                                 s_x[bsub][nq + 2], s_x[bsub][nq + 3]);
        } else {
            #pragma unroll
            for (int c = 0; c < 4; ++c)
                if (nq + c < nend) orow[s_oidx[nq + c]] = s_x[bsub][nq + c];
        }
    }
}

// ---------------------------------------------------------------------------
// Tier-3 fallback (tiny ws): direct uncoalesced gather. Correct, slow.
// ---------------------------------------------------------------------------
__global__ __launch_bounds__(128) void gather_fallback(const float* __restrict__ tape,
                                                       const float* __restrict__ weights,
                                                       const float* __restrict__ bias,
                                                       const int*   __restrict__ in_idx,
                                                       const int*   __restrict__ out_idx,
                                                       const int*   __restrict__ act_type,
                                                       float* __restrict__ out) {
    const int n = blockIdx.x;
    const int b = threadIdx.x;
    float acc = 0.f;
    for (int f = 0; f < F_SZ; ++f) {
        acc += tape[(size_t)b * TAPE_SZ + in_idx[(size_t)n * F_SZ + f]] *
               weights[(size_t)n * F_SZ + f];
    }
    acc += bias[n];
    acc = (act_type[n] == 0) ? fmaxf(acc, 0.f) : tanhf(acc);
    out[(size_t)b * TAPE_SZ + out_idx[n]] = acc;
}

__global__ __launch_bounds__(256) void copy_tail_fb(const float* __restrict__ tape,
                                                    float* __restrict__ out) {
    const int n4 = (TAPE_SZ - N_SZ) / 4;
    int i = blockIdx.x * blockDim.x + threadIdx.x;
    int b = blockIdx.y;
    if (i < n4) {
        const float4* src = (const float4*)(tape + (size_t)b * TAPE_SZ + N_SZ);
        float4*       dst = (float4*)(out  + (size_t)b * TAPE_SZ + N_SZ);
        dst[i] = src[i];
    }
}

extern "C" void kernel_launch(void* const* d_in, const int* in_sizes, int n_in,
                              void* d_out, int out_size, void* d_ws, size_t ws_size,
                              hipStream_t stream) {
    const float* tape    = (const float*)d_in[0];
    const float* weights = (const float*)d_in[1];
    const float* bias    = (const float*)d_in[2];
    const int*   in_idx  = (const int*)d_in[3];
    const int*   out_idx = (const int*)d_in[4];
    const int*   act     = (const int*)d_in[5];
    float*       out     = (float*)d_out;

    const size_t one = (size_t)TAPE_SZ * B_SZ * sizeof(unsigned short);   // 25.6 MB
    if (ws_size >= 2 * one) {
        unsigned short* tapeF = (unsigned short*)d_ws;
        transpose_full<<<dim3(TAPE_SZ / 32), dim3(32, 8), 0, stream>>>(tape, tapeF);
        void* args[] = {(void*)&tapeF, (void*)&weights, (void*)&bias, (void*)&in_idx,
                        (void*)&out_idx, (void*)&act, (void*)&tape, (void*)&out};
        hipError_t e = hipLaunchCooperativeKernel((const void*)gather_phased,
                                                  dim3(GRID_G), dim3(256),
                                                  args, 0, stream);
        if (e != hipSuccess) {
            // Cooperative launch unavailable: proven R1 path into 2nd ws half.
            unsigned short* tapeP = tapeF + (size_t)TAPE_SZ * B_SZ;
            transpose_part<<<dim3(TAPE_SZ / 32), dim3(32, 8), 0, stream>>>(tape, tapeP);
            gather_mm_part<<<dim3(NGATH2 + NTAIL), dim3(256), 0, stream>>>(
                tapeP, weights, bias, in_idx, out_idx, act, tape, out);
        }
    } else if (ws_size >= one) {
        unsigned short* tapeT = (unsigned short*)d_ws;
        transpose_part<<<dim3(TAPE_SZ / 32), dim3(32, 8), 0, stream>>>(tape, tapeT);
        gather_mm_part<<<dim3(NGATH2 + NTAIL), dim3(256), 0, stream>>>(
            tapeT, weights, bias, in_idx, out_idx, act, tape, out);
    } else {
        copy_tail_fb<<<dim3(((TAPE_SZ - N_SZ) / 4 + 255) / 256, B_SZ), 256, 0, stream>>>(tape, out);
        gather_fallback<<<dim3(N_SZ), 128, 0, stream>>>(
            tape, weights, bias, in_idx, out_idx, act, out);
    }
}

// Round 8
// 197.257 us; speedup vs baseline: 2.4325x; 2.4325x over previous
//
#include <hip/hip_runtime.h>
#include <cmath>

#define TAPE_SZ 100000
#define N_SZ    50000
#define F_SZ    32
#define B_SZ    128
#define GSUB    64         // b's per group: row-segment = 64*2B = one full 128-B line
#define RANGE   25000      // 4 ranges; live slice/group = 25000*128B = 3.2 MB -> L2-fit
#define NBV     128        // n's per gather block
#define NCHUNK  391        // ceil(50000/128); last chunk has 80 n's
#define GRID_G  (NCHUNK*2) // x2 b-groups = 782 blocks (~3/CU, one generation)

// Manual round-to-nearest-even f32 -> bf16 bits.
static __device__ __forceinline__ unsigned short f32_to_bf16(float f) {
    unsigned int u = __float_as_uint(f);
    u = (u + 0x7fffu + ((u >> 16) & 1u)) >> 16;
    return (unsigned short)u;
}

// ---------------------------------------------------------------------------
// Transpose tape (B x TAPE fp32) -> tapeG[g][row][64b] bf16 (g = b/64).
// Each group's 12.8-MB region is contiguous: within a 25000-row range the
// slice is a contiguous 3.2 MB -> maps across ALL L2 sets (R6's aliasing fix).
// Columns >= N_SZ also write the fp32 tail straight into out (tile already
// staged in LDS). R7 bugfix: guard is PER-COLUMN (x0 + tx >= N_SZ), so the
// boundary tile straddling N_SZ=50000 (x0=49984) copies cols 50000..50015.
// ---------------------------------------------------------------------------
__global__ __launch_bounds__(256) void transpose_g64(const float* __restrict__ in,
                                                     unsigned short* __restrict__ outG,
                                                     float* __restrict__ out) {
    __shared__ float tile[32][129];
    const int x0 = blockIdx.x * 32;
    const int tx = threadIdx.x;       // tape-col 0..31
    const int ty = threadIdx.y;       // 0..7

    #pragma unroll
    for (int yy = ty; yy < B_SZ; yy += 8)
        tile[tx][yy] = in[(size_t)yy * TAPE_SZ + x0 + tx];
    __syncthreads();

    const int tid = ty * 32 + tx;
    const int l = tid >> 3;           // row-in-tile 0..31
    const int o = tid & 7;            // 16-b chunk 0..7
    const int g = o >> 2;             // b-group
    const int j = o & 3;              // chunk within group
    unsigned short* dst = outG + ((size_t)g * TAPE_SZ + x0 + l) * GSUB + j * 16;
    union { unsigned short u[8]; uint4 q; } p0, p1;
    #pragma unroll
    for (int k = 0; k < 8; ++k) {
        p0.u[k] = f32_to_bf16(tile[l][g * GSUB + j * 16 + k]);
        p1.u[k] = f32_to_bf16(tile[l][g * GSUB + j * 16 + 8 + k]);
    }
    *(uint4*)dst       = p0.q;
    *(uint4*)(dst + 8) = p1.q;

    // ---- fp32 tail: columns [N_SZ, TAPE_SZ) survive into out (per-column) ----
    if (x0 + tx >= N_SZ) {
        #pragma unroll
        for (int yy = ty; yy < B_SZ; yy += 8)
            out[(size_t)yy * TAPE_SZ + x0 + tx] = tile[tx][yy];
    }
}

// ---------------------------------------------------------------------------
// Gather-matmul, full-line segments + soft-phased ranges.
// Block = (chunk of 128 n, b-group g). Thread = (n_local, b-quad q): 2 uint4
// (32 B) per entry; 4 lanes/n consume one full 128-B line -> 3.2M distinct
// line fetches total (vs 12.8M in the 32-B-segment design). Entries counting-
// sorted into 4 range buckets; ranges processed in order with block-level
// __syncthreads only -> co-resident blocks stay approx in the same range,
// keeping each XCD's 3.2-MB slice L2-resident. No grid.sync.
// ---------------------------------------------------------------------------
__global__ __launch_bounds__(512, 4) void gather_g64(
    const unsigned short* __restrict__ tapeG,
    const float* __restrict__ weights,
    const float* __restrict__ bias,
    const int*   __restrict__ in_idx,
    const int*   __restrict__ out_idx,
    const int*   __restrict__ act_type,
    float* __restrict__ out) {
    __shared__ union {
        struct {
            uint2 ent[NBV][33];    // sorted (.x = tape idx, .y = weight bits); pitch 33
            int   start[NBV][5];   // bucket boundaries per n (start[.][4] = total)
        } s;                       // 36352 B
        float x[GSUB][132];        // epilogue stage [b_local][n], aliased (33792 B)
    } u;
    __shared__ int   s_oidx[NBV];
    __shared__ float s_bias[NBV];
    __shared__ int   s_act[NBV];

    const int tid   = threadIdx.x;
    const int g     = blockIdx.x & 1;     // b-group; XCD parity under %8 round-robin
    const int chunk = blockIdx.x >> 1;
    const int n0    = chunk * NBV;
    const int nend  = min(NBV, N_SZ - n0);

    // ---- stage + counting-sort entries by range (one thread per n) ----
    if (tid < NBV) {
        if (tid < nend) {
            const int*   ip = in_idx  + (size_t)(n0 + tid) * 32;
            const float* wp = weights + (size_t)(n0 + tid) * 32;
            int ix[32];
            #pragma unroll
            for (int f = 0; f < 32; ++f) ix[f] = ip[f];
            int c0 = 0, c1 = 0, c2 = 0, c3 = 0;
            #pragma unroll
            for (int f = 0; f < 32; ++f) {
                const int r = ix[f] / RANGE;
                c0 += (r == 0); c1 += (r == 1); c2 += (r == 2); c3 += (r == 3);
            }
            int o0 = 0, o1 = c0, o2 = c0 + c1, o3 = c0 + c1 + c2;
            u.s.start[tid][0] = 0;  u.s.start[tid][1] = o1;
            u.s.start[tid][2] = o2; u.s.start[tid][3] = o3;
            u.s.start[tid][4] = 32;
            #pragma unroll
            for (int f = 0; f < 32; ++f) {
                const int r = ix[f] / RANGE;
                int pos;
                if      (r == 0) pos = o0++;
                else if (r == 1) pos = o1++;
                else if (r == 2) pos = o2++;
                else             pos = o3++;
                u.s.ent[tid][pos] = make_uint2((unsigned)ix[f], __float_as_uint(wp[f]));
            }
            s_oidx[tid] = out_idx[n0 + tid];
            s_bias[tid] = bias[n0 + tid];
            s_act[tid]  = act_type[n0 + tid];
        } else {
            #pragma unroll
            for (int r = 0; r < 5; ++r) u.s.start[tid][r] = 0;
        }
    }
    __syncthreads();

    const int nl = tid >> 2;              // n_local 0..127
    const int q  = tid & 3;               // b-quad: b_sub = 16q .. 16q+15
    const unsigned short* tg = tapeG + (size_t)g * TAPE_SZ * GSUB + q * 16;

    float a[16];
    #pragma unroll
    for (int k = 0; k < 16; ++k) a[k] = 0.f;

    #pragma unroll 1
    for (int r = 0; r < 4; ++r) {
        const int e1 = u.s.start[nl][r + 1];
        for (int e = u.s.start[nl][r]; e < e1; ++e) {
            const uint2 iw = u.s.ent[nl][e];
            const unsigned short* p = tg + (size_t)iw.x * GSUB;
            const uint4 q0 = *(const uint4*)(p);
            const uint4 q1 = *(const uint4*)(p + 8);
            const float wv = __uint_as_float(iw.y);
#define ACC8(Q, B0) \
            a[B0+0] = fmaf(__uint_as_float((Q).x << 16),          wv, a[B0+0]); \
            a[B0+1] = fmaf(__uint_as_float((Q).x & 0xffff0000u),  wv, a[B0+1]); \
            a[B0+2] = fmaf(__uint_as_float((Q).y << 16),          wv, a[B0+2]); \
            a[B0+3] = fmaf(__uint_as_float((Q).y & 0xffff0000u),  wv, a[B0+3]); \
            a[B0+4] = fmaf(__uint_as_float((Q).z << 16),          wv, a[B0+4]); \
            a[B0+5] = fmaf(__uint_as_float((Q).z & 0xffff0000u),  wv, a[B0+5]); \
            a[B0+6] = fmaf(__uint_as_float((Q).w << 16),          wv, a[B0+6]); \
            a[B0+7] = fmaf(__uint_as_float((Q).w & 0xffff0000u),  wv, a[B0+7]);
            ACC8(q0, 0) ACC8(q1, 8)
#undef ACC8
        }
        __syncthreads();   // block-level phase alignment (uniform: all threads, 4x)
    }

    // ---- bias + activation ----
    {
        const float bz = (nl < nend) ? s_bias[nl] : 0.f;
        const int   at = (nl < nend) ? s_act[nl]  : 0;
        #pragma unroll
        for (int k = 0; k < 16; ++k) {
            const float v = a[k] + bz;
            a[k] = (at == 0) ? fmaxf(v, 0.f) : tanhf(v);
        }
    }
    __syncthreads();   // all ent/start reads complete before aliased x writes
    if (nl < nend) {
        #pragma unroll
        for (int k = 0; k < 16; ++k)
            u.x[q * 16 + k][nl] = a[k];
    }
    __syncthreads();

    // ---- epilogue: coalesced float4 row stores (consec out_idx fast path) ----
    const int quads = (nend + 3) >> 2;
    for (int it = tid; it < GSUB * quads; it += 512) {
        int bsub, j4;
        if (nend == NBV) { bsub = it >> 5; j4 = it & 31; }
        else             { bsub = it / quads; j4 = it - bsub * quads; }
        const int nq  = j4 * 4;
        const int oc0 = s_oidx[nq];
        float* orow = out + (size_t)(g * GSUB + bsub) * TAPE_SZ;
        const bool consec = (nq + 3 < nend) &&
                            (s_oidx[nq + 1] == oc0 + 1) &&
                            (s_oidx[nq + 2] == oc0 + 2) &&
                            (s_oidx[nq + 3] == oc0 + 3) && ((oc0 & 3) == 0);
        if (consec) {
            *(float4*)(orow + oc0) = *(const float4*)&u.x[bsub][nq];
        } else {
            #pragma unroll
            for (int c = 0; c < 4; ++c)
                if (nq + c < nend) orow[s_oidx[nq + c]] = u.x[bsub][nq + c];
        }
    }
}

// ---------------------------------------------------------------------------
// Fallback (workspace too small): direct uncoalesced gather. Correct, slow.
// ---------------------------------------------------------------------------
__global__ __launch_bounds__(128) void gather_fallback(const float* __restrict__ tape,
                                                       const float* __restrict__ weights,
                                                       const float* __restrict__ bias,
                                                       const int*   __restrict__ in_idx,
                                                       const int*   __restrict__ out_idx,
                                                       const int*   __restrict__ act_type,
                                                       float* __restrict__ out) {
    const int n = blockIdx.x;
    const int b = threadIdx.x;
    float acc = 0.f;
    for (int f = 0; f < F_SZ; ++f) {
        acc += tape[(size_t)b * TAPE_SZ + in_idx[(size_t)n * F_SZ + f]] *
               weights[(size_t)n * F_SZ + f];
    }
    acc += bias[n];
    acc = (act_type[n] == 0) ? fmaxf(acc, 0.f) : tanhf(acc);
    out[(size_t)b * TAPE_SZ + out_idx[n]] = acc;
}

__global__ __launch_bounds__(256) void copy_tail_fb(const float* __restrict__ tape,
                                                    float* __restrict__ out) {
    const int n4 = (TAPE_SZ - N_SZ) / 4;
    int i = blockIdx.x * blockDim.x + threadIdx.x;
    int b = blockIdx.y;
    if (i < n4) {
        const float4* src = (const float4*)(tape + (size_t)b * TAPE_SZ + N_SZ);
        float4*       dst = (float4*)(out  + (size_t)b * TAPE_SZ + N_SZ);
        dst[i] = src[i];
    }
}

extern "C" void kernel_launch(void* const* d_in, const int* in_sizes, int n_in,
                              void* d_out, int out_size, void* d_ws, size_t ws_size,
                              hipStream_t stream) {
    const float* tape    = (const float*)d_in[0];
    const float* weights = (const float*)d_in[1];
    const float* bias    = (const float*)d_in[2];
    const int*   in_idx  = (const int*)d_in[3];
    const int*   out_idx = (const int*)d_in[4];
    const int*   act     = (const int*)d_in[5];
    float*       out     = (float*)d_out;

    const size_t need = (size_t)TAPE_SZ * B_SZ * sizeof(unsigned short);   // 25.6 MB
    if (ws_size >= need) {
        unsigned short* tapeG = (unsigned short*)d_ws;
        transpose_g64<<<dim3(TAPE_SZ / 32), dim3(32, 8), 0, stream>>>(tape, tapeG, out);
        gather_g64<<<dim3(GRID_G), dim3(512), 0, stream>>>(
            tapeG, weights, bias, in_idx, out_idx, act, out);
    } else {
        copy_tail_fb<<<dim3(((TAPE_SZ - N_SZ) / 4 + 255) / 256, B_SZ), 256, 0, stream>>>(tape, out);
        gather_fallback<<<dim3(N_SZ), 128, 0, stream>>>(
            tape, weights, bias, in_idx, out_idx, act, out);
    }
}

// Round 9
// 193.932 us; speedup vs baseline: 2.4742x; 1.0171x over previous
//
#include <hip/hip_runtime.h>
#include <cmath>

#define TAPE_SZ 100000
#define N_SZ    50000
#define F_SZ    32
#define B_SZ    128
#define GSUB    64         // b's per group: row-segment = 64*2B = one full 128-B line
#define RANGE   25000      // 4 ranges; live slice/group = 25000*128B = 3.2 MB -> L2-fit
#define NBV     128        // n's per gather block
#define NCHUNK  391        // ceil(50000/128); last chunk has 80 n's
#define GRID_G  (NCHUNK*2) // x2 b-groups = 782 blocks (~3/CU, one generation)

// Manual round-to-nearest-even f32 -> bf16 bits.
static __device__ __forceinline__ unsigned short f32_to_bf16(float f) {
    unsigned int u = __float_as_uint(f);
    u = (u + 0x7fffu + ((u >> 16) & 1u)) >> 16;
    return (unsigned short)u;
}

// ---------------------------------------------------------------------------
// Transpose tape (B x TAPE fp32) -> tapeG[g][row][64b] bf16 (g = b/64).
// Contiguous per-group region (no L2 set-aliasing). Columns >= N_SZ write the
// fp32 tail straight into out (per-column guard: R7 bugfix, R8-verified).
// ---------------------------------------------------------------------------
__global__ __launch_bounds__(256) void transpose_g64(const float* __restrict__ in,
                                                     unsigned short* __restrict__ outG,
                                                     float* __restrict__ out) {
    __shared__ float tile[32][129];
    const int x0 = blockIdx.x * 32;
    const int tx = threadIdx.x;       // tape-col 0..31
    const int ty = threadIdx.y;       // 0..7

    #pragma unroll
    for (int yy = ty; yy < B_SZ; yy += 8)
        tile[tx][yy] = in[(size_t)yy * TAPE_SZ + x0 + tx];
    __syncthreads();

    const int tid = ty * 32 + tx;
    const int l = tid >> 3;           // row-in-tile 0..31
    const int o = tid & 7;            // 16-b chunk 0..7
    const int g = o >> 2;             // b-group
    const int j = o & 3;              // chunk within group
    unsigned short* dst = outG + ((size_t)g * TAPE_SZ + x0 + l) * GSUB + j * 16;
    union { unsigned short u[8]; uint4 q; } p0, p1;
    #pragma unroll
    for (int k = 0; k < 8; ++k) {
        p0.u[k] = f32_to_bf16(tile[l][g * GSUB + j * 16 + k]);
        p1.u[k] = f32_to_bf16(tile[l][g * GSUB + j * 16 + 8 + k]);
    }
    *(uint4*)dst       = p0.q;
    *(uint4*)(dst + 8) = p1.q;

    // ---- fp32 tail: columns [N_SZ, TAPE_SZ) survive into out (per-column) ----
    if (x0 + tx >= N_SZ) {
        #pragma unroll
        for (int yy = ty; yy < B_SZ; yy += 8)
            out[(size_t)yy * TAPE_SZ + x0 + tx] = tile[tx][yy];
    }
}

// ---------------------------------------------------------------------------
// Gather-matmul: full-line segments + soft-phased ranges + BATCHED loads.
// R9 delta vs R8 (only change): the per-range entry loop is software-
// pipelined in batches of 4 entries -> 8 independent dwordx4 loads issue
// before the first FMA waits on them (MLP 2 -> 8 per wave). R8's profile
// (27% VALU, 13% HBM, 3.2M lines, flat vs R4) showed a serial
// LDS->VMEM->FMA chain exposing ~400-cyc latency per entry.
// ---------------------------------------------------------------------------
__global__ __launch_bounds__(512, 4) void gather_g64(
    const unsigned short* __restrict__ tapeG,
    const float* __restrict__ weights,
    const float* __restrict__ bias,
    const int*   __restrict__ in_idx,
    const int*   __restrict__ out_idx,
    const int*   __restrict__ act_type,
    float* __restrict__ out) {
    __shared__ union {
        struct {
            uint2 ent[NBV][33];    // sorted (.x = tape idx, .y = weight bits); pitch 33
            int   start[NBV][5];   // bucket boundaries per n (start[.][4] = total)
        } s;                       // 36352 B
        float x[GSUB][132];        // epilogue stage [b_local][n], aliased (33792 B)
    } u;
    __shared__ int   s_oidx[NBV];
    __shared__ float s_bias[NBV];
    __shared__ int   s_act[NBV];

    const int tid   = threadIdx.x;
    const int g     = blockIdx.x & 1;     // b-group; XCD parity under %8 round-robin
    const int chunk = blockIdx.x >> 1;
    const int n0    = chunk * NBV;
    const int nend  = min(NBV, N_SZ - n0);

    // ---- stage + counting-sort entries by range (one thread per n) ----
    if (tid < NBV) {
        if (tid < nend) {
            const int*   ip = in_idx  + (size_t)(n0 + tid) * 32;
            const float* wp = weights + (size_t)(n0 + tid) * 32;
            int ix[32];
            #pragma unroll
            for (int f = 0; f < 32; ++f) ix[f] = ip[f];
            int c0 = 0, c1 = 0, c2 = 0, c3 = 0;
            #pragma unroll
            for (int f = 0; f < 32; ++f) {
                const int r = ix[f] / RANGE;
                c0 += (r == 0); c1 += (r == 1); c2 += (r == 2); c3 += (r == 3);
            }
            int o0 = 0, o1 = c0, o2 = c0 + c1, o3 = c0 + c1 + c2;
            u.s.start[tid][0] = 0;  u.s.start[tid][1] = o1;
            u.s.start[tid][2] = o2; u.s.start[tid][3] = o3;
            u.s.start[tid][4] = 32;
            #pragma unroll
            for (int f = 0; f < 32; ++f) {
                const int r = ix[f] / RANGE;
                int pos;
                if      (r == 0) pos = o0++;
                else if (r == 1) pos = o1++;
                else if (r == 2) pos = o2++;
                else             pos = o3++;
                u.s.ent[tid][pos] = make_uint2((unsigned)ix[f], __float_as_uint(wp[f]));
            }
            s_oidx[tid] = out_idx[n0 + tid];
            s_bias[tid] = bias[n0 + tid];
            s_act[tid]  = act_type[n0 + tid];
        } else {
            #pragma unroll
            for (int r = 0; r < 5; ++r) u.s.start[tid][r] = 0;
        }
    }
    __syncthreads();

    const int nl = tid >> 2;              // n_local 0..127
    const int q  = tid & 3;               // b-quad: b_sub = 16q .. 16q+15
    const unsigned short* tg = tapeG + (size_t)g * TAPE_SZ * GSUB + q * 16;

    float a[16];
    #pragma unroll
    for (int k = 0; k < 16; ++k) a[k] = 0.f;

#define ACC8(Q, B0, WV) \
    a[B0+0] = fmaf(__uint_as_float((Q).x << 16),          WV, a[B0+0]); \
    a[B0+1] = fmaf(__uint_as_float((Q).x & 0xffff0000u),  WV, a[B0+1]); \
    a[B0+2] = fmaf(__uint_as_float((Q).y << 16),          WV, a[B0+2]); \
    a[B0+3] = fmaf(__uint_as_float((Q).y & 0xffff0000u),  WV, a[B0+3]); \
    a[B0+4] = fmaf(__uint_as_float((Q).z << 16),          WV, a[B0+4]); \
    a[B0+5] = fmaf(__uint_as_float((Q).z & 0xffff0000u),  WV, a[B0+5]); \
    a[B0+6] = fmaf(__uint_as_float((Q).w << 16),          WV, a[B0+6]); \
    a[B0+7] = fmaf(__uint_as_float((Q).w & 0xffff0000u),  WV, a[B0+7]);

    #pragma unroll 1
    for (int r = 0; r < 4; ++r) {
        const int e1 = u.s.start[nl][r + 1];
        int e = u.s.start[nl][r];
        // ---- batch-4: 8 dwordx4 loads in flight before the first FMA wait ----
        for (; e + 3 < e1; e += 4) {
            uint2 iw4[4];
            #pragma unroll
            for (int j = 0; j < 4; ++j) iw4[j] = u.s.ent[nl][e + j];
            uint4 qa[4], qb[4];
            #pragma unroll
            for (int j = 0; j < 4; ++j) {
                const unsigned short* p = tg + (size_t)iw4[j].x * GSUB;
                qa[j] = *(const uint4*)(p);
                qb[j] = *(const uint4*)(p + 8);
            }
            #pragma unroll
            for (int j = 0; j < 4; ++j) {
                const float wv = __uint_as_float(iw4[j].y);
                ACC8(qa[j], 0, wv) ACC8(qb[j], 8, wv)
            }
        }
        // ---- remainder (<= 3 entries) ----
        for (; e < e1; ++e) {
            const uint2 iw = u.s.ent[nl][e];
            const unsigned short* p = tg + (size_t)iw.x * GSUB;
            const uint4 q0 = *(const uint4*)(p);
            const uint4 q1 = *(const uint4*)(p + 8);
            const float wv = __uint_as_float(iw.y);
            ACC8(q0, 0, wv) ACC8(q1, 8, wv)
        }
        __syncthreads();   // block-level phase alignment (uniform: all threads, 4x)
    }
#undef ACC8

    // ---- bias + activation ----
    {
        const float bz = (nl < nend) ? s_bias[nl] : 0.f;
        const int   at = (nl < nend) ? s_act[nl]  : 0;
        #pragma unroll
        for (int k = 0; k < 16; ++k) {
            const float v = a[k] + bz;
            a[k] = (at == 0) ? fmaxf(v, 0.f) : tanhf(v);
        }
    }
    __syncthreads();   // all ent/start reads complete before aliased x writes
    if (nl < nend) {
        #pragma unroll
        for (int k = 0; k < 16; ++k)
            u.x[q * 16 + k][nl] = a[k];
    }
    __syncthreads();

    // ---- epilogue: coalesced float4 row stores (consec out_idx fast path) ----
    const int quads = (nend + 3) >> 2;
    for (int it = tid; it < GSUB * quads; it += 512) {
        int bsub, j4;
        if (nend == NBV) { bsub = it >> 5; j4 = it & 31; }
        else             { bsub = it / quads; j4 = it - bsub * quads; }
        const int nq  = j4 * 4;
        const int oc0 = s_oidx[nq];
        float* orow = out + (size_t)(g * GSUB + bsub) * TAPE_SZ;
        const bool consec = (nq + 3 < nend) &&
                            (s_oidx[nq + 1] == oc0 + 1) &&
                            (s_oidx[nq + 2] == oc0 + 2) &&
                            (s_oidx[nq + 3] == oc0 + 3) && ((oc0 & 3) == 0);
        if (consec) {
            *(float4*)(orow + oc0) = *(const float4*)&u.x[bsub][nq];
        } else {
            #pragma unroll
            for (int c = 0; c < 4; ++c)
                if (nq + c < nend) orow[s_oidx[nq + c]] = u.x[bsub][nq + c];
        }
    }
}

// ---------------------------------------------------------------------------
// Fallback (workspace too small): direct uncoalesced gather. Correct, slow.
// ---------------------------------------------------------------------------
__global__ __launch_bounds__(128) void gather_fallback(const float* __restrict__ tape,
                                                       const float* __restrict__ weights,
                                                       const float* __restrict__ bias,
                                                       const int*   __restrict__ in_idx,
                                                       const int*   __restrict__ out_idx,
                                                       const int*   __restrict__ act_type,
                                                       float* __restrict__ out) {
    const int n = blockIdx.x;
    const int b = threadIdx.x;
    float acc = 0.f;
    for (int f = 0; f < F_SZ; ++f) {
        acc += tape[(size_t)b * TAPE_SZ + in_idx[(size_t)n * F_SZ + f]] *
               weights[(size_t)n * F_SZ + f];
    }
    acc += bias[n];
    acc = (act_type[n] == 0) ? fmaxf(acc, 0.f) : tanhf(acc);
    out[(size_t)b * TAPE_SZ + out_idx[n]] = acc;
}

__global__ __launch_bounds__(256) void copy_tail_fb(const float* __restrict__ tape,
                                                    float* __restrict__ out) {
    const int n4 = (TAPE_SZ - N_SZ) / 4;
    int i = blockIdx.x * blockDim.x + threadIdx.x;
    int b = blockIdx.y;
    if (i < n4) {
        const float4* src = (const float4*)(tape + (size_t)b * TAPE_SZ + N_SZ);
        float4*       dst = (float4*)(out  + (size_t)b * TAPE_SZ + N_SZ);
        dst[i] = src[i];
    }
}

extern "C" void kernel_launch(void* const* d_in, const int* in_sizes, int n_in,
                              void* d_out, int out_size, void* d_ws, size_t ws_size,
                              hipStream_t stream) {
    const float* tape    = (const float*)d_in[0];
    const float* weights = (const float*)d_in[1];
    const float* bias    = (const float*)d_in[2];
    const int*   in_idx  = (const int*)d_in[3];
    const int*   out_idx = (const int*)d_in[4];
    const int*   act     = (const int*)d_in[5];
    float*       out     = (float*)d_out;

    const size_t need = (size_t)TAPE_SZ * B_SZ * sizeof(unsigned short);   // 25.6 MB
    if (ws_size >= need) {
        unsigned short* tapeG = (unsigned short*)d_ws;
        transpose_g64<<<dim3(TAPE_SZ / 32), dim3(32, 8), 0, stream>>>(tape, tapeG, out);
        gather_g64<<<dim3(GRID_G), dim3(512), 0, stream>>>(
            tapeG, weights, bias, in_idx, out_idx, act, out);
    } else {
        copy_tail_fb<<<dim3(((TAPE_SZ - N_SZ) / 4 + 255) / 256, B_SZ), 256, 0, stream>>>(tape, out);
        gather_fallback<<<dim3(N_SZ), 128, 0, stream>>>(
            tape, weights, bias, in_idx, out_idx, act, out);
    }
}

// Round 10
// 185.471 us; speedup vs baseline: 2.5870x; 1.0456x over previous
//
#include <hip/hip_runtime.h>
#include <cmath>

#define TAPE_SZ 100000
#define N_SZ    50000
#define F_SZ    32
#define B_SZ    128
#define NRANGE  8          // ranges; live slice = 12500 rows * 256 B = 3.2 MB -> fits every XCD L2
#define RANGE   12500
#define NBV     64         // n's per gather block
#define NCHUNK  ((N_SZ + NBV - 1) / NBV)   // 782 blocks = one generation (~3-4/CU)

// Manual round-to-nearest-even f32 -> bf16 bits.
static __device__ __forceinline__ unsigned short f32_to_bf16(float f) {
    unsigned int u = __float_as_uint(f);
    u = (u + 0x7fffu + ((u >> 16) & 1u)) >> 16;
    return (unsigned short)u;
}

// ---------------------------------------------------------------------------
// Transpose tape (B x TAPE fp32) -> tapeR[row][128b] bf16 (full 256-B rows).
// Columns >= N_SZ write the fp32 tail straight into out (per-column guard).
// ---------------------------------------------------------------------------
__global__ __launch_bounds__(256) void transpose_rows(const float* __restrict__ in,
                                                      unsigned short* __restrict__ outR,
                                                      float* __restrict__ out) {
    __shared__ float tile[32][129];
    const int x0 = blockIdx.x * 32;
    const int tx = threadIdx.x;       // tape-col 0..31
    const int ty = threadIdx.y;       // 0..7

    #pragma unroll
    for (int yy = ty; yy < B_SZ; yy += 8)
        tile[tx][yy] = in[(size_t)yy * TAPE_SZ + x0 + tx];
    __syncthreads();

    const int tid = ty * 32 + tx;
    const int l = tid >> 3;           // row-in-tile 0..31
    const int o = tid & 7;            // 8-b chunk 0..7
    unsigned short* dst = outR + (size_t)(x0 + l) * B_SZ + o * 8;
    union { unsigned short u[8]; uint4 q; } p0, p1;
    #pragma unroll
    for (int k = 0; k < 8; ++k) {
        p0.u[k] = f32_to_bf16(tile[l][o * 8 + k]);
        p1.u[k] = f32_to_bf16(tile[l][64 + o * 8 + k]);
    }
    *(uint4*)dst        = p0.q;
    *(uint4*)(dst + 64) = p1.q;

    // ---- fp32 tail: columns [N_SZ, TAPE_SZ) survive into out (per-column) ----
    if (x0 + tx >= N_SZ) {
        #pragma unroll
        for (int yy = ty; yy < B_SZ; yy += 8)
            out[(size_t)yy * TAPE_SZ + x0 + tx] = tile[tx][yy];
    }
}

// ---------------------------------------------------------------------------
// Gather-matmul: probe-minimal full-row reads + 8-range soft phasing.
// Thread = (n_pair, seg s): 16 consecutive lanes x 16 B cover one whole 256-B
// row -> 4x 64-B granule-probes per (n,f) = 6.4M total (the floor; every
// 83-89us design issued 12.8M). Entries bucket-sorted into 8 row-ranges
// (byte-packed u64 counters -> no scratch); ranges swept in order with
// block-level syncs so the live 3.2-MB slice stays L2-resident per XCD.
// ---------------------------------------------------------------------------
__global__ __launch_bounds__(512, 8) void gather_rows(
    const unsigned short* __restrict__ tapeR,
    const float* __restrict__ weights,
    const float* __restrict__ bias,
    const int*   __restrict__ in_idx,
    const int*   __restrict__ out_idx,
    const int*   __restrict__ act_type,
    float* __restrict__ out) {
    __shared__ union {
        struct {
            uint2 ent[NBV][33];          // sorted (.x = row, .y = weight bits); pitch 33
            int   start[NBV][NRANGE + 1];
        } s;                             // 19200 B
        float x[B_SZ][65];               // epilogue stage [b][n_local], aliased (33280 B)
    } u;
    __shared__ int   s_oidx[NBV];
    __shared__ float s_bias[NBV];
    __shared__ int   s_act[NBV];

    const int tid  = threadIdx.x;
    const int n0   = blockIdx.x * NBV;
    const int nend = min(NBV, N_SZ - n0);

    // ---- stage + 8-bucket counting sort (one thread per n; u64 byte-packed) ----
    if (tid < NBV) {
        if (tid < nend) {
            const int*   ip = in_idx  + (size_t)(n0 + tid) * 32;
            const float* wp = weights + (size_t)(n0 + tid) * 32;
            int ix[32];
            #pragma unroll
            for (int f = 0; f < 32; ++f) ix[f] = ip[f];
            unsigned long long c = 0ull;
            #pragma unroll
            for (int f = 0; f < 32; ++f) c += 1ull << (8 * (ix[f] / RANGE));
            int off[NRANGE + 1];
            off[0] = 0;
            #pragma unroll
            for (int r = 0; r < NRANGE; ++r)
                off[r + 1] = off[r] + (int)((c >> (8 * r)) & 255u);
            #pragma unroll
            for (int r = 0; r <= NRANGE; ++r) u.s.start[tid][r] = off[r];
            unsigned long long p = 0ull;
            #pragma unroll
            for (int r = 0; r < NRANGE; ++r)
                p |= (unsigned long long)off[r] << (8 * r);
            #pragma unroll
            for (int f = 0; f < 32; ++f) {
                const int r   = ix[f] / RANGE;
                const int pos = (int)((p >> (8 * r)) & 255u);
                p += 1ull << (8 * r);
                u.s.ent[tid][pos] = make_uint2((unsigned)ix[f], __float_as_uint(wp[f]));
            }
            s_oidx[tid] = out_idx[n0 + tid];
            s_bias[tid] = bias[n0 + tid];
            s_act[tid]  = act_type[n0 + tid];
        } else {
            #pragma unroll
            for (int r = 0; r <= NRANGE; ++r) u.s.start[tid][r] = 0;
        }
    }
    __syncthreads();

    const int s  = tid & 15;              // row segment: b = 8s .. 8s+7
    const int nl = tid >> 4;              // 0..31; thread owns n_local nl and nl+32
    const unsigned short* tp = tapeR + s * 8;

    float aA[8], aB[8];
    #pragma unroll
    for (int k = 0; k < 8; ++k) { aA[k] = 0.f; aB[k] = 0.f; }

#define ACC8(Q, A, WV) \
    A[0] = fmaf(__uint_as_float((Q).x << 16),          WV, A[0]); \
    A[1] = fmaf(__uint_as_float((Q).x & 0xffff0000u),  WV, A[1]); \
    A[2] = fmaf(__uint_as_float((Q).y << 16),          WV, A[2]); \
    A[3] = fmaf(__uint_as_float((Q).y & 0xffff0000u),  WV, A[3]); \
    A[4] = fmaf(__uint_as_float((Q).z << 16),          WV, A[4]); \
    A[5] = fmaf(__uint_as_float((Q).z & 0xffff0000u),  WV, A[5]); \
    A[6] = fmaf(__uint_as_float((Q).w << 16),          WV, A[6]); \
    A[7] = fmaf(__uint_as_float((Q).w & 0xffff0000u),  WV, A[7]);

    #pragma unroll 1
    for (int r = 0; r < NRANGE; ++r) {
        // ---- n_a = n0 + nl ----
        {
            const int e1 = u.s.start[nl][r + 1];
            int e = u.s.start[nl][r];
            for (; e + 1 < e1; e += 2) {
                const uint2 w0 = u.s.ent[nl][e];
                const uint2 w1 = u.s.ent[nl][e + 1];
                const uint4 q0 = *(const uint4*)(tp + (size_t)w0.x * B_SZ);
                const uint4 q1 = *(const uint4*)(tp + (size_t)w1.x * B_SZ);
                const float v0 = __uint_as_float(w0.y), v1 = __uint_as_float(w1.y);
                ACC8(q0, aA, v0) ACC8(q1, aA, v1)
            }
            if (e < e1) {
                const uint2 w0 = u.s.ent[nl][e];
                const uint4 q0 = *(const uint4*)(tp + (size_t)w0.x * B_SZ);
                const float v0 = __uint_as_float(w0.y);
                ACC8(q0, aA, v0)
            }
        }
        // ---- n_b = n0 + nl + 32 ----
        {
            const int e1 = u.s.start[nl + 32][r + 1];
            int e = u.s.start[nl + 32][r];
            for (; e + 1 < e1; e += 2) {
                const uint2 w0 = u.s.ent[nl + 32][e];
                const uint2 w1 = u.s.ent[nl + 32][e + 1];
                const uint4 q0 = *(const uint4*)(tp + (size_t)w0.x * B_SZ);
                const uint4 q1 = *(const uint4*)(tp + (size_t)w1.x * B_SZ);
                const float v0 = __uint_as_float(w0.y), v1 = __uint_as_float(w1.y);
                ACC8(q0, aB, v0) ACC8(q1, aB, v1)
            }
            if (e < e1) {
                const uint2 w0 = u.s.ent[nl + 32][e];
                const uint4 q0 = *(const uint4*)(tp + (size_t)w0.x * B_SZ);
                const float v0 = __uint_as_float(w0.y);
                ACC8(q0, aB, v0)
            }
        }
        __syncthreads();   // phase alignment; also fences ent reads before x writes
    }
#undef ACC8

    // ---- bias + activation (register-only) ----
    if (nl < nend) {
        const float bz = s_bias[nl];
        const int   at = s_act[nl];
        #pragma unroll
        for (int k = 0; k < 8; ++k) {
            const float v = aA[k] + bz;
            aA[k] = (at == 0) ? fmaxf(v, 0.f) : tanhf(v);
        }
    }
    if (nl + 32 < nend) {
        const float bz = s_bias[nl + 32];
        const int   at = s_act[nl + 32];
        #pragma unroll
        for (int k = 0; k < 8; ++k) {
            const float v = aB[k] + bz;
            aB[k] = (at == 0) ? fmaxf(v, 0.f) : tanhf(v);
        }
    }

    // (last phase's __syncthreads ended all ent/start reads -> safe to alias)
    if (nl < nend) {
        #pragma unroll
        for (int k = 0; k < 8; ++k) u.x[s * 8 + k][nl] = aA[k];
    }
    if (nl + 32 < nend) {
        #pragma unroll
        for (int k = 0; k < 8; ++k) u.x[s * 8 + k][nl + 32] = aB[k];
    }
    __syncthreads();

    // ---- epilogue: coalesced float4 row stores (consec out_idx fast path) ----
    const int quads = (nend + 3) >> 2;
    for (int it = tid; it < B_SZ * quads; it += 512) {
        int b, j4;
        if (nend == NBV) { b = it >> 4; j4 = it & 15; }
        else             { b = it / quads; j4 = it - b * quads; }
        const int nq  = j4 * 4;
        const int oc0 = s_oidx[nq];
        float* orow = out + (size_t)b * TAPE_SZ;
        const bool consec = (nq + 3 < nend) &&
                            (s_oidx[nq + 1] == oc0 + 1) &&
                            (s_oidx[nq + 2] == oc0 + 2) &&
                            (s_oidx[nq + 3] == oc0 + 3) && ((oc0 & 3) == 0);
        if (consec) {
            *(float4*)(orow + oc0) = make_float4(u.x[b][nq + 0], u.x[b][nq + 1],
                                                 u.x[b][nq + 2], u.x[b][nq + 3]);
        } else {
            #pragma unroll
            for (int c = 0; c < 4; ++c)
                if (nq + c < nend) orow[s_oidx[nq + c]] = u.x[b][nq + c];
        }
    }
}

// ---------------------------------------------------------------------------
// Fallback (workspace too small): direct uncoalesced gather. Correct, slow.
// ---------------------------------------------------------------------------
__global__ __launch_bounds__(128) void gather_fallback(const float* __restrict__ tape,
                                                       const float* __restrict__ weights,
                                                       const float* __restrict__ bias,
                                                       const int*   __restrict__ in_idx,
                                                       const int*   __restrict__ out_idx,
                                                       const int*   __restrict__ act_type,
                                                       float* __restrict__ out) {
    const int n = blockIdx.x;
    const int b = threadIdx.x;
    float acc = 0.f;
    for (int f = 0; f < F_SZ; ++f) {
        acc += tape[(size_t)b * TAPE_SZ + in_idx[(size_t)n * F_SZ + f]] *
               weights[(size_t)n * F_SZ + f];
    }
    acc += bias[n];
    acc = (act_type[n] == 0) ? fmaxf(acc, 0.f) : tanhf(acc);
    out[(size_t)b * TAPE_SZ + out_idx[n]] = acc;
}

__global__ __launch_bounds__(256) void copy_tail_fb(const float* __restrict__ tape,
                                                    float* __restrict__ out) {
    const int n4 = (TAPE_SZ - N_SZ) / 4;
    int i = blockIdx.x * blockDim.x + threadIdx.x;
    int b = blockIdx.y;
    if (i < n4) {
        const float4* src = (const float4*)(tape + (size_t)b * TAPE_SZ + N_SZ);
        float4*       dst = (float4*)(out  + (size_t)b * TAPE_SZ + N_SZ);
        dst[i] = src[i];
    }
}

extern "C" void kernel_launch(void* const* d_in, const int* in_sizes, int n_in,
                              void* d_out, int out_size, void* d_ws, size_t ws_size,
                              hipStream_t stream) {
    const float* tape    = (const float*)d_in[0];
    const float* weights = (const float*)d_in[1];
    const float* bias    = (const float*)d_in[2];
    const int*   in_idx  = (const int*)d_in[3];
    const int*   out_idx = (const int*)d_in[4];
    const int*   act     = (const int*)d_in[5];
    float*       out     = (float*)d_out;

    const size_t need = (size_t)TAPE_SZ * B_SZ * sizeof(unsigned short);   // 25.6 MB
    if (ws_size >= need) {
        unsigned short* tapeR = (unsigned short*)d_ws;
        transpose_rows<<<dim3(TAPE_SZ / 32), dim3(32, 8), 0, stream>>>(tape, tapeR, out);
        gather_rows<<<dim3(NCHUNK), dim3(512), 0, stream>>>(
            tapeR, weights, bias, in_idx, out_idx, act, out);
    } else {
        copy_tail_fb<<<dim3(((TAPE_SZ - N_SZ) / 4 + 255) / 256, B_SZ), 256, 0, stream>>>(tape, out);
        gather_fallback<<<dim3(N_SZ), 128, 0, stream>>>(
            tape, weights, bias, in_idx, out_idx, act, out);
    }
}